// Round 3
// baseline (27147.903 us; speedup 1.0000x reference)
//
#include <hip/hip_runtime.h>

// BRITS fused persistent-RNN kernel for MI355X (gfx950) — v4 "balanced phases".
//
// v3 post-mortem: VGPR_Count=128 even with the cap lifted -> compiler CHOSE 128,
// so v2/v3 never spilled. v1(reg weights)==v2(LDS weights)==12.7ms proves the
// limiter is the phase skeleton: 2-of-8 waves on the serial chain, shfl-split
// dots, ~3K cy of real work in a ~30K cy step (VALUBusy 10%), idle-driven.
//
// v4 structure (512 thr = 8 waves, 2 seqs/block, grid 256):
//  - One gate row-instance PER LANE: wave w -> seq s=w>>2, role v=w&3,
//    gate row ri=v*64+l, full K=192 in registers (128 Wih + 64 Whh). No shfl.
//  - 4 balanced phases/step, both seqs symmetric:
//    P1: all: phh=Whh.hd | v0: xh->xc + delta/gamma_x(t+1)
//    P2: v1: zh,ch,cc,outputs | v2: gamma_h(t+1) | v3: land x/m(t+1), alpha(t+1),
//        issue x/m(t+2)
//    P3: all: gate = gbias+phh+Wih.[cc;m] -> gt_s
//    P4: v0: LSTM pointwise -> h,hd
//  - Small mats (Whr/Wfr/Wdh/WwcA/WwcB) in LDS, 16-slot XOR swizzle
//    slot=(k4^(row&15)) so a 16-lane phase covers each bank exactly 2x
//    (the old k4^(row&7) left rows 8 apart colliding -> 1.68e8 conflicts).
//  - Register policy pinned: flat_work_group_size(512,512)+waves_per_eu(2,2)
//    => VGPR cap 256; opaque asm on each weight reg blocks remat/shaving.
//  - 4 raw barriers/step (lgkmcnt drain only, no vmcnt drain).

constexpr int NB = 256;   // batch
constexpr int NT = 1024;  // time
constexpr int ND = 64;    // features D (= H)
constexpr int NG = 256;   // 4*H gate width
constexpr int K2 = 128;   // 2*D

__device__ __forceinline__ float sgm(float v){ return 1.0f/(1.0f+__expf(-v)); }
__device__ __forceinline__ float tnh(float v){
  float a = fabsf(v);
  float e = __expf(-2.0f*a);
  float t = (1.0f-e)/(1.0f+e);
  return v < 0.0f ? -t : t;
}

// raw barrier: drain own LDS ops, then s_barrier. No vmcnt(0) drain.
__device__ __forceinline__ void bar(){
  asm volatile("s_waitcnt lgkmcnt(0)" ::: "memory");
  __builtin_amdgcn_s_barrier();
}

// y = sum_k M[row][k]*act[k], K=64. Row layout: Msw[row*64 + ((k4^(row&15))<<2)+i].
// act is wave-uniform (broadcast, conflict-free).
__device__ __forceinline__ float dotw(const float* __restrict__ wrow, int sw16,
                                      const float* __restrict__ act){
  float a0=0.f,a1=0.f,a2=0.f,a3=0.f;
  #pragma unroll
  for (int k4=0;k4<16;++k4){
    const float4 wv = *(const float4*)(wrow + ((k4^sw16)<<2));
    const float4 av = *(const float4*)(act + (k4<<2));
    a0=fmaf(wv.x,av.x,a0); a1=fmaf(wv.y,av.y,a1);
    a2=fmaf(wv.z,av.z,a2); a3=fmaf(wv.w,av.w,a3);
  }
  return (a0+a1)+(a2+a3);
}

__global__ __attribute__((amdgpu_flat_work_group_size(512,512),
                          amdgpu_waves_per_eu(2,2)))
void brits_fused(
    const float* __restrict__ x_g, const float* __restrict__ m_g,
    const float* __restrict__ Wih_g, const float* __restrict__ Whh_g,
    const float* __restrict__ bih_g, const float* __restrict__ bhh_g,
    const float* __restrict__ Wdh_g, const float* __restrict__ bdh_g,
    const float* __restrict__ wdx_g, const float* __restrict__ bdx_g,
    const float* __restrict__ Whr_g, const float* __restrict__ bhr_g,
    const float* __restrict__ Wfr_g, const float* __restrict__ bfr_g,
    const float* __restrict__ Wwc_g, const float* __restrict__ bwc_g,
    float* __restrict__ out0, float* __restrict__ pred)
{
  const int tid = threadIdx.x;
  const int l   = tid & 63;                                   // lane
  const int w   = __builtin_amdgcn_readfirstlane(tid >> 6);   // wave 0..7
  const int s   = w >> 2;                                     // sequence 0/1
  const int v   = w & 3;                                      // role 0..3
  const int ri  = v*64 + l;                                   // gate row 0..255
  const int sw16= l & 15;                                     // LDS swizzle key
  const int bid = blockIdx.x;
  const int dir = bid >> 7;                                   // 0=fwd, 1=bwd
  const int pair = bid & 127;
  const int bb  = pair*2 + s;                                 // this wave's batch row

  const float* Wih_d = Wih_g + (size_t)dir*NG*K2;
  const float* Whh_d = Whh_g + (size_t)dir*NG*ND;
  const float* bih_d = bih_g + dir*NG;
  const float* bhh_d = bhh_g + dir*NG;
  const float* Wdh_d = Wdh_g + dir*ND*ND;
  const float* bdh_d = bdh_g + dir*ND;
  const float* wdx_d = wdx_g + dir*ND;
  const float* bdx_d = bdx_g + dir*ND;
  const float* Whr_d = Whr_g + dir*ND*ND;
  const float* bhr_d = bhr_g + dir*ND;
  const float* Wfr_d = Wfr_g + dir*ND*ND;
  const float* bfr_d = bfr_g + dir*ND;
  const float* Wwc_d = Wwc_g + dir*ND*K2;
  const float* bwc_d = bwc_g + dir*ND;

  // ---- LDS: 5 swizzled 64x64 weight mats (80 KB) + activation staging ----
  __shared__ __align__(16) float Whr_sw [64*64];
  __shared__ __align__(16) float Wfr_sw [64*64];  // diag zeroed at staging
  __shared__ __align__(16) float Wdh_sw [64*64];
  __shared__ __align__(16) float WwcA_sw[64*64];  // Wwc[:, 0:64]   (gamma_x half)
  __shared__ __align__(16) float WwcB_sw[64*64];  // Wwc[:, 64:128] (mask half)
  __shared__ __align__(16) float h_s [2][ND];
  __shared__ __align__(16) float hd_s[2][ND];     // h * gamma_h
  __shared__ __align__(16) float xh_s[2][ND];
  __shared__ __align__(16) float xc_s[2][ND];
  __shared__ __align__(16) float cc_s[2][ND];
  __shared__ __align__(16) float dl_s[2][ND];     // delta(t+1)
  __shared__ __align__(16) float gx_s[2][ND];     // gamma_x(t+1)
  __shared__ __align__(16) float gh_s[2][ND];     // gamma_h(t+1)
  __shared__ __align__(16) float al_s[2][2][ND];  // alpha [parity][seq]
  __shared__ __align__(16) float gt_s[2][NG];     // gate preactivations
  __shared__ __align__(16) float xb_s[2][2][ND];  // x double-buffer [parity][seq]
  __shared__ __align__(16) float mb_s[2][2][ND];  // m double-buffer

  // ---- stage small mats into swizzled LDS (each wave: k4 = 2w, 2w+1) ----
  #pragma unroll
  for (int q=0;q<2;++q){
    const int k4 = 2*w + q;                 // 0..15 across the 8 waves
    const int dst = ((k4 ^ sw16) << 2);
    float4 t4;
    t4 = *(const float4*)(Whr_d + l*ND + 4*k4);  *(float4*)(Whr_sw  + l*64 + dst) = t4;
    t4 = *(const float4*)(Wdh_d + l*ND + 4*k4);  *(float4*)(Wdh_sw  + l*64 + dst) = t4;
    t4 = *(const float4*)(Wfr_d + l*ND + 4*k4);
    { const int c = 4*k4;                   // zero diagonal of feat_reg
      if (c   == l) t4.x = 0.f;
      if (c+1 == l) t4.y = 0.f;
      if (c+2 == l) t4.z = 0.f;
      if (c+3 == l) t4.w = 0.f; }
    *(float4*)(Wfr_sw + l*64 + dst) = t4;
    t4 = *(const float4*)(Wwc_d + l*K2 + 4*k4);       *(float4*)(WwcA_sw + l*64 + dst) = t4;
    t4 = *(const float4*)(Wwc_d + l*K2 + 64 + 4*k4);  *(float4*)(WwcB_sw + l*64 + dst) = t4;
  }

  // ---- gate weights: full K=192 per lane, pinned in registers ----
  float wih[K2];   // Wih[ri][0..127]  ([cc ; m] halves)
  float whh[ND];   // Whh[ri][0..63]
  #pragma unroll
  for (int k=0;k<K2;k+=4){
    const float4 t4 = *(const float4*)(Wih_d + (size_t)ri*K2 + k);
    wih[k]=t4.x; wih[k+1]=t4.y; wih[k+2]=t4.z; wih[k+3]=t4.w;
  }
  #pragma unroll
  for (int k=0;k<ND;k+=4){
    const float4 t4 = *(const float4*)(Whh_d + (size_t)ri*ND + k);
    whh[k]=t4.x; whh[k+1]=t4.y; whh[k+2]=t4.z; whh[k+3]=t4.w;
  }
  // opaque touch: forbid remat/reload of the weight registers
  #pragma unroll
  for (int k=0;k<K2;++k) asm volatile("" : "+v"(wih[k]));
  #pragma unroll
  for (int k=0;k<ND;++k) asm volatile("" : "+v"(whh[k]));
  const float gbias = bih_d[ri] + bhh_d[ri];

  // per-role scalars + LDS row pointers
  float bhr_l=0.f, wdx_l=0.f, bdx_l=0.f, bfr_l=0.f, bdh_l=0.f, bwc_l=0.f;
  if (v==0){ bhr_l = bhr_d[l]; wdx_l = wdx_d[l]; bdx_l = bdx_d[l]; }
  if (v==1){ bfr_l = bfr_d[l]; }
  if (v==2){ bdh_l = bdh_d[l]; }
  if (v==3){ bwc_l = bwc_d[l]; }
  const float* whr_row  = Whr_sw  + l*64;
  const float* wfr_row  = Wfr_sw  + l*64;
  const float* wdh_row  = Wdh_sw  + l*64;
  const float* wwcA_row = WwcA_sw + l*64;
  const float* wwcB_row = WwcB_sw + l*64;

  float cst = 0.f;            // LSTM cell state (v0, lane l, own seq)
  float dlt = 0.f;            // delta carry     (v0)
  float xr  = 0.f, mr = 0.f;  // x/m prefetch    (v3), data for step t+1

  const size_t NBTD   = (size_t)NB*NT*ND;
  const size_t plane0 = (size_t)(0+dir)*NBTD;   // ch
  const size_t plane2 = (size_t)(2+dir)*NBTD;   // zh
  const size_t plane4 = (size_t)(4+dir)*NBTD;   // xh

  // ---- prologue ----
  if (v==0){
    h_s[s][l]=0.f; hd_s[s][l]=0.f;
    gx_s[s][l] = __expf(-fmaxf(0.f, bdx_l));    // gamma_x(0): delta=0
  }
  if (v==3){
    const int t0 = dir ? (NT-1) : 0;
    const size_t ib0 = ((size_t)bb*NT + t0)*ND + l;
    xb_s[0][s][l] = x_g[ib0];
    mb_s[0][s][l] = m_g[ib0];
    const int t1 = dir ? (NT-2) : 1;
    const size_t ib1 = ((size_t)bb*NT + t1)*ND + l;
    xr = x_g[ib1];                               // step-1 data, lands at t=0 P2
    mr = m_g[ib1];
  }
  bar();
  if (v==3){                                     // alpha(0)
    const float pa = dotw(wwcA_row, sw16, &gx_s[s][0]);
    const float pb = dotw(wwcB_row, sw16, &mb_s[0][s][0]);
    al_s[0][s][l] = sgm(bwc_l + pa + pb);
  }
  bar();

  for (int t=0; t<NT; ++t){
    const int cur = t & 1;
    const int nxt = cur ^ 1;
    const int tm  = dir ? (NT-1-t) : t;
    const size_t ob = ((size_t)bb*NT + tm)*ND + l;

    // ======== P1: all: phh | v0: xh -> xc + delta/gamma_x(t+1) ========
    float phh;
    {
      float a0=0.f,a1=0.f,a2=0.f,a3=0.f;
      #pragma unroll
      for (int k=0;k<ND;k+=4){
        const float4 av = *(const float4*)(&hd_s[s][k]);
        a0=fmaf(whh[k  ],av.x,a0); a1=fmaf(whh[k+1],av.y,a1);
        a2=fmaf(whh[k+2],av.z,a2); a3=fmaf(whh[k+3],av.w,a3);
      }
      phh=(a0+a1)+(a2+a3);
    }
    if (v==0){
      const float xh = bhr_l + dotw(whr_row, sw16, &h_s[s][0]);
      xh_s[s][l] = xh;
      pred[plane4 + ob] = xh;
      const float mm = mb_s[cur][s][l];
      const float xx = xb_s[cur][s][l];
      xc_s[s][l] = mm*xx + (1.f-mm)*xh;
      dlt = 1.0f + (1.0f-mm)*dlt;               // delta(t+1)
      dl_s[s][l] = dlt;
      gx_s[s][l] = __expf(-fmaxf(0.f, fmaf(dlt, wdx_l, bdx_l)));  // gamma_x(t+1)
    }
    bar();

    // ======== P2: v1: zh/ch/cc + outputs | v2: gamma_h(t+1) | v3: prefetch+alpha ========
    if (v==1){
      const float xh = xh_s[s][l];
      const float zh = bfr_l + dotw(wfr_row, sw16, &xc_s[s][0]);
      pred[plane2 + ob] = zh;
      const float a  = al_s[cur][s][l];
      const float ch = a*zh + (1.f-a)*xh;
      const float mm = mb_s[cur][s][l];
      const float xx = xb_s[cur][s][l];
      const float cc = mm*xx + (1.f-mm)*ch;
      cc_s[s][l] = cc;
      pred[plane0 + ob] = ch;
      atomicAdd(&out0[ob], 0.5f*cc);            // mean over the two directions
    } else if (v==2){
      if (t+1 < NT){
        gh_s[s][l] = __expf(-fmaxf(0.f, bdh_l + dotw(wdh_row, sw16, &dl_s[s][0])));
      }
    } else if (v==3){
      if (t+1 < NT){
        xb_s[nxt][s][l] = xr;                   // land t+1 (loaded last step)
        mb_s[nxt][s][l] = mr;
        // alpha(t+1) = sgm(Wwc.[gamma_x(t+1); m(t+1)] + bwc)
        const float pa = dotw(wwcA_row, sw16, &gx_s[s][0]);
        const float pb = dotw(wwcB_row, sw16, &mb_s[nxt][s][0]);
        al_s[nxt][s][l] = sgm(bwc_l + pa + pb);
        if (t+2 < NT){                          // issue t+2 (full-step cover)
          const int tn = dir ? (NT-3-t) : (t+2);
          const size_t ib = ((size_t)bb*NT + tn)*ND + l;
          xr = x_g[ib];
          mr = m_g[ib];
        }
      }
    }
    bar();

    // ======== P3: all: gate row ri = gbias + phh + Wih.[cc ; m] ========
    {
      float a0=0.f,a1=0.f,a2=0.f,a3=0.f;
      #pragma unroll
      for (int k=0;k<ND;k+=4){
        const float4 av = *(const float4*)(&cc_s[s][k]);
        a0=fmaf(wih[k  ],av.x,a0); a1=fmaf(wih[k+1],av.y,a1);
        a2=fmaf(wih[k+2],av.z,a2); a3=fmaf(wih[k+3],av.w,a3);
      }
      #pragma unroll
      for (int k=0;k<ND;k+=4){
        const float4 av = *(const float4*)(&mb_s[cur][s][k]);
        a0=fmaf(wih[64+k  ],av.x,a0); a1=fmaf(wih[64+k+1],av.y,a1);
        a2=fmaf(wih[64+k+2],av.z,a2); a3=fmaf(wih[64+k+3],av.w,a3);
      }
      gt_s[s][ri] = gbias + phh + (a0+a1)+(a2+a3);
    }
    bar();

    // ======== P4: v0: LSTM pointwise ========
    if (v==0){
      const float gi = gt_s[s][l];
      const float gf = gt_s[s][64+l];
      const float gg = gt_s[s][128+l];
      const float go = gt_s[s][192+l];
      cst = sgm(gf)*cst + sgm(gi)*tnh(gg);
      const float hn = sgm(go)*tnh(cst);
      h_s[s][l]  = hn;
      hd_s[s][l] = hn * gh_s[s][l];             // gamma_h(t+1) from P2
    }
    bar();
  }
}

extern "C" void kernel_launch(void* const* d_in, const int* in_sizes, int n_in,
                              void* d_out, int out_size, void* d_ws, size_t ws_size,
                              hipStream_t stream) {
  (void)in_sizes; (void)n_in; (void)d_ws; (void)ws_size; (void)out_size;
  const float* x   = (const float*)d_in[0];
  const float* m   = (const float*)d_in[1];
  const float* Wih = (const float*)d_in[2];
  const float* Whh = (const float*)d_in[3];
  const float* bih = (const float*)d_in[4];
  const float* bhh = (const float*)d_in[5];
  const float* Wdh = (const float*)d_in[6];
  const float* bdh = (const float*)d_in[7];
  const float* wdx = (const float*)d_in[8];
  const float* bdx = (const float*)d_in[9];
  const float* Whr = (const float*)d_in[10];
  const float* bhr = (const float*)d_in[11];
  const float* Wfr = (const float*)d_in[12];
  const float* bfr = (const float*)d_in[13];
  const float* Wwc = (const float*)d_in[14];
  const float* bwc = (const float*)d_in[15];

  float* out  = (float*)d_out;                       // [B,T,D,1] mean imputation
  float* pred = out + (size_t)NB*NT*ND;              // [6,B,T,D,1]

  // out0 is accumulated by both directions via atomicAdd -> zero it first
  // (d_out is re-poisoned before every timed launch).
  hipMemsetAsync(out, 0, (size_t)NB*NT*ND*sizeof(float), stream);

  brits_fused<<<dim3(256), dim3(512), 0, stream>>>(
      x, m, Wih, Whh, bih, bhh, Wdh, bdh, wdx, bdx,
      Whr, bhr, Wfr, bfr, Wwc, bwc, out, pred);
}